// Round 12
// baseline (44.523 us; speedup 1.0000x reference)
//
#include <hip/hip_runtime.h>

#define NREL1  12   // NREL + 1 relation matrices
#define NN     128  // neighbours
#define EE     128  // in-features
#define FF     128  // out-features
#define BV     192  // B * V
#define RK     (NREL1 * EE)   // 1536

// ws layout (floats): [0, 3072) wa (Wa1[12][128] | Wa2[12][128])
#define WS_WA  0

// K0: wa rows (wave per (r,e), coalesced W read once aggregate).
__global__ __launch_bounds__(256) void prep_kernel(const float* __restrict__ W,
                                                   const float* __restrict__ a,
                                                   float* __restrict__ ws) {
    const int w    = blockIdx.x * 4 + (threadIdx.x >> 6);  // 1536 waves
    const int lane = threadIdx.x & 63;
    const int r = w >> 7, e = w & 127;
    const float2 wv = *(const float2*)(W + (size_t)(r * EE + e) * FF + lane * 2);
    const float2 a1 = *(const float2*)(a + lane * 2);
    const float2 a2 = *(const float2*)(a + FF + lane * 2);
    float d1 = wv.x * a1.x + wv.y * a1.y;
    float d2 = wv.x * a2.x + wv.y * a2.y;
#pragma unroll
    for (int off = 32; off; off >>= 1) {
        d1 += __shfl_xor(d1, off);
        d2 += __shfl_xor(d2, off);
    }
    if (lane == 0) {
        ws[WS_WA + r * EE + e]      = d1;
        ws[WS_WA + RK + r * EE + e] = d2;
    }
}

// K1: block per bv, 1024 threads (16 waves), 37 KB LDS.
// prefetch 8 edges/wave (lane holds float2 of ne AND fe) -> logits
// (64-lane butterfly) -> redundant per-wave softmax (no LDS, no barrier)
// -> LDS-atomic scatter into ONE S accumulator -> Phase D: out = S @ W.
__global__ __launch_bounds__(1024) void gat_fused(const float* __restrict__ fe,
                                                  const float* __restrict__ ne,
                                                  const int* __restrict__ widx,
                                                  const float* __restrict__ ind,
                                                  const float* __restrict__ W,
                                                  const float* __restrict__ ws_r,
                                                  float* __restrict__ out) {
    __shared__ float wa[2 * RK];     // 12 KB
    __shared__ float s1[RK];         // 6 KB  (single S accumulator)
    __shared__ float red[32][FF];    // 16 KB
    __shared__ float red2[4][FF];    // 2 KB
    __shared__ float e_lds[NN];      // 0.5 KB
    __shared__ int   idx[NN];        // 0.5 KB

    const int bv   = blockIdx.x;
    const int tid  = threadIdx.x;
    const int wave = tid >> 6;
    const int lane = tid & 63;

    const float* ne_bv = ne + (size_t)bv * NN * EE;
    const float* fe_bv = fe + (size_t)bv * NN * EE;

    if (tid < NN) idx[tid] = widx[bv * NN + tid];

    // prefetch: 8 edges per wave; lane owns e-pair (lane*2, lane*2+1) of BOTH
    float2 xn[8], xf[8];
#pragma unroll
    for (int i = 0; i < 8; ++i) {
        const int n = wave * 8 + i;
        xn[i] = *(const float2*)(ne_bv + (size_t)n * EE + lane * 2);
        xf[i] = *(const float2*)(fe_bv + (size_t)n * EE + lane * 2);
    }

    // stage wa (L2) -> LDS; zero the S accumulator
    if (tid < 2 * RK / 4)
        ((float4*)wa)[tid] = ((const float4*)(ws_r + WS_WA))[tid];
    if (tid < RK / 4)
        ((float4*)s1)[tid] = make_float4(0.f, 0.f, 0.f, 0.f);
    __syncthreads();

    // Phase A: logits; every lane contributes ne.wa1 + fe.wa2 partials
#pragma unroll
    for (int i = 0; i < 8; ++i) {
        const int n = wave * 8 + i;
        const int r = idx[n];
        const float2 w1 = *(const float2*)&wa[r * EE + lane * 2];
        const float2 w2 = *(const float2*)&wa[RK + r * EE + lane * 2];
        float d = xn[i].x * w1.x + xn[i].y * w1.y
                + xf[i].x * w2.x + xf[i].y * w2.y;
#pragma unroll
        for (int off = 32; off; off >>= 1) d += __shfl_xor(d, off);
        if (lane == 0) e_lds[n] = d > 0.f ? d : 0.2f * d;
    }
    __syncthreads();

    // Phase B: redundant per-wave softmax + indicator (no barrier after)
    float a0, a1;
    {
        const float v0 = e_lds[lane], v1 = e_lds[lane + 64];
        float m = fmaxf(v0, v1);
#pragma unroll
        for (int off = 32; off; off >>= 1) m = fmaxf(m, __shfl_xor(m, off));
        const float ex0 = __expf(v0 - m), ex1 = __expf(v1 - m);
        float ss = ex0 + ex1;
#pragma unroll
        for (int off = 32; off; off >>= 1) ss += __shfl_xor(ss, off);
        const float inv = 1.f / ss;
        a0 = ex0 * inv * ind[bv * NN + lane];
        a1 = ex1 * inv * ind[bv * NN + lane + 64];
    }

    // Phase C: LDS-atomic scatter, all 64 lanes, 2 ds_add per edge
#pragma unroll
    for (int i = 0; i < 8; ++i) {
        const int n  = wave * 8 + i;                  // wave-uniform
        const float an = (wave < 8) ? __shfl(a0, n) : __shfl(a1, n - 64);
        const int r  = idx[n];
        float* p = &s1[r * EE + lane * 2];
        atomicAdd(p + 0, an * xn[i].x);
        atomicAdd(p + 1, an * xn[i].y);
    }
    __syncthreads();

    // Phase D: out[bv][f] = sum_k S[k] * W[k][f]
    // thread = (kg 0..31 owns 48 k's, fq 0..31 owns 4 f). W from L2.
    {
        const int fq = tid & 31;
        const int kg = tid >> 5;
        float4 acc = {0.f, 0.f, 0.f, 0.f};
        const float* Wp = W + (size_t)(kg * 48) * FF + fq * 4;
        const float* Sp = &s1[kg * 48];
#pragma unroll 4
        for (int j = 0; j < 48; ++j) {
            const float sv = Sp[j];
            const float4 w4 = *(const float4*)(Wp + (size_t)j * FF);
            acc.x += sv * w4.x; acc.y += sv * w4.y;
            acc.z += sv * w4.z; acc.w += sv * w4.w;
        }
        *(float4*)&red[kg][fq * 4] = acc;
    }
    __syncthreads();
    if (tid < 512) {
        const int f = tid & 127, h = tid >> 7;
        float v = 0.f;
#pragma unroll
        for (int j = 0; j < 8; ++j) v += red[h * 8 + j][f];
        red2[h][f] = v;
    }
    __syncthreads();
    if (tid < FF)
        out[bv * FF + tid] = red2[0][tid] + red2[1][tid] + red2[2][tid] + red2[3][tid];
}

extern "C" void kernel_launch(void* const* d_in, const int* in_sizes, int n_in,
                              void* d_out, int out_size, void* d_ws, size_t ws_size,
                              hipStream_t stream) {
    const float* fe  = (const float*)d_in[0];  // feature_embed   (B,V,N,E)
    const float* ne  = (const float*)d_in[1];  // neighbour_embed (B,V,N,E)
    const int*   wi  = (const int*)d_in[2];    // w_index (B,V,N)
    const float* ind = (const float*)d_in[3];  // indicator (B,V,N)
    const float* W   = (const float*)d_in[4];  // (12,E,F)
    const float* a   = (const float*)d_in[5];  // (2F,1)
    float* out = (float*)d_out;                // (B,V,F)
    float* ws  = (float*)d_ws;

    prep_kernel<<<RK / 4, 256, 0, stream>>>(W, a, ws);
    gat_fused<<<BV, 1024, 0, stream>>>(fe, ne, wi, ind, W, ws, out);
}

// Round 14
// 26.066 us; speedup vs baseline: 1.7081x; 1.7081x over previous
//
#include <hip/hip_runtime.h>

#define NREL1  12   // NREL + 1 relation matrices
#define NN     128  // neighbours
#define EE     128  // in-features
#define FF     128  // out-features
#define BV     192  // B * V
#define RK     (NREL1 * EE)   // 1536

// ws layout (floats): [0, 3072) wa (Wa1[12][128] | Wa2[12][128])
#define WS_WA  0

// K0: wa rows (wave per (r,e), coalesced W read once aggregate).
__global__ __launch_bounds__(256) void prep_kernel(const float* __restrict__ W,
                                                   const float* __restrict__ a,
                                                   float* __restrict__ ws) {
    const int w    = blockIdx.x * 4 + (threadIdx.x >> 6);  // 1536 waves
    const int lane = threadIdx.x & 63;
    const int r = w >> 7, e = w & 127;
    const float2 wv = *(const float2*)(W + (size_t)(r * EE + e) * FF + lane * 2);
    const float2 a1 = *(const float2*)(a + lane * 2);
    const float2 a2 = *(const float2*)(a + FF + lane * 2);
    float d1 = wv.x * a1.x + wv.y * a1.y;
    float d2 = wv.x * a2.x + wv.y * a2.y;
#pragma unroll
    for (int off = 32; off; off >>= 1) {
        d1 += __shfl_xor(d1, off);
        d2 += __shfl_xor(d2, off);
    }
    if (lane == 0) {
        ws[WS_WA + r * EE + e]      = d1;
        ws[WS_WA + RK + r * EE + e] = d2;
    }
}

// K1: block per bv, 1024 threads (16 waves).
// prefetch 8 edges/wave to regs (lanes<32 ne, >=32 fe) -> logits (64-lane
// butterfly) -> per-wave redundant softmax (registers only, no barrier) ->
// attn broadcast hoisted to FULL wave (shfl source lanes must be active!)
// -> predicated scatter into per-wave LDS copy -> reduce 16 copies ->
// Phase D: out = S @ W with S preloaded via ds_read_b128.
__global__ __launch_bounds__(1024) void gat_fused(const float* __restrict__ fe,
                                                  const float* __restrict__ ne,
                                                  const int* __restrict__ widx,
                                                  const float* __restrict__ ind,
                                                  const float* __restrict__ W,
                                                  const float* __restrict__ ws_r,
                                                  float* __restrict__ out) {
    __shared__ float wa[2 * RK];     // 12 KB
    __shared__ float s16[16][RK];    // 96 KB; s16[0] holds S after reduce
    __shared__ float red[32][FF];    // 16 KB
    __shared__ float red2[4][FF];    // 2 KB
    __shared__ float e_lds[NN];      // 0.5 KB
    __shared__ int   idx[NN];        // 0.5 KB

    const int bv   = blockIdx.x;
    const int tid  = threadIdx.x;
    const int wave = tid >> 6;
    const int lane = tid & 63;
    const int l32  = lane & 31;
    const int half = lane >> 5;   // 0: ne/wa1 side, 1: fe/wa2 side

    const float* ne_bv = ne + (size_t)bv * NN * EE;
    const float* fe_bv = fe + (size_t)bv * NN * EE;

    if (tid < NN) idx[tid] = widx[bv * NN + tid];

    // prefetch: 8 edges per wave, lane holds one e-quad of ne (or fe)
    float4 xr[8];
    {
        const float* base = (half ? fe_bv : ne_bv) + l32 * 4;
#pragma unroll
        for (int i = 0; i < 8; ++i)
            xr[i] = *(const float4*)(base + (wave * 8 + i) * EE);
    }

    // stage wa (L2) -> LDS (1 float4/thread); zero scatter copies (6/thread)
    if (tid < 2 * RK / 4)
        ((float4*)wa)[tid] = ((const float4*)(ws_r + WS_WA))[tid];
    {
        const float4 z = {0.f, 0.f, 0.f, 0.f};
#pragma unroll
        for (int q = 0; q < 6; ++q)
            ((float4*)&s16[0][0])[q * 1024 + tid] = z;
    }
    __syncthreads();

    // Phase A: logits; lanes<32 contribute ne.wa1, lanes>=32 fe.wa2
#pragma unroll
    for (int i = 0; i < 8; ++i) {
        const int n = wave * 8 + i;
        const int r = idx[n];
        const float4 wq = *(const float4*)&wa[half * RK + r * EE + l32 * 4];
        float d = xr[i].x * wq.x + xr[i].y * wq.y + xr[i].z * wq.z + xr[i].w * wq.w;
#pragma unroll
        for (int off = 32; off; off >>= 1) d += __shfl_xor(d, off);
        if (lane == 0) e_lds[n] = d > 0.f ? d : 0.2f * d;
    }
    __syncthreads();

    // Phase B: per-wave redundant softmax + indicator, registers only
    float a0, a1;
    {
        const float v0 = e_lds[lane], v1 = e_lds[lane + 64];
        float m = fmaxf(v0, v1);
#pragma unroll
        for (int off = 32; off; off >>= 1) m = fmaxf(m, __shfl_xor(m, off));
        const float ex0 = __expf(v0 - m), ex1 = __expf(v1 - m);
        float ss = ex0 + ex1;
#pragma unroll
        for (int off = 32; off; off >>= 1) ss += __shfl_xor(ss, off);
        const float inv = 1.f / ss;
        a0 = ex0 * inv * ind[bv * NN + lane];
        a1 = ex1 * inv * ind[bv * NN + lane + 64];
    }

    // attn broadcast for this wave's 8 edges: ALL 64 lanes participate
    // (shfl from a lane that is inactive is undefined -- R13 bug)
    float anv[8];
#pragma unroll
    for (int i = 0; i < 8; ++i) {
        const int n = wave * 8 + i;                        // wave-uniform
        anv[i] = (wave < 8) ? __shfl(a0, n) : __shfl(a1, n - 64);
    }

    // Phase C: predicated scatter from regs into this wave's private copy
    if (half == 0) {
        float* sc = s16[wave];
#pragma unroll
        for (int i = 0; i < 8; ++i) {
            const int n = wave * 8 + i;
            float* p = sc + idx[n] * EE + l32 * 4;
            float4 cur = *(const float4*)p;
            cur.x += anv[i] * xr[i].x; cur.y += anv[i] * xr[i].y;
            cur.z += anv[i] * xr[i].z; cur.w += anv[i] * xr[i].w;
            *(float4*)p = cur;
        }
    }
    __syncthreads();

    // reduce 16 copies -> S in s16[0] (in place)
    if (tid < RK / 4) {
        float4 v = *(const float4*)&s16[0][tid * 4];
#pragma unroll
        for (int c = 1; c < 16; ++c) {
            const float4 t = *(const float4*)&s16[c][tid * 4];
            v.x += t.x; v.y += t.y; v.z += t.z; v.w += t.w;
        }
        *(float4*)&s16[0][tid * 4] = v;
    }
    __syncthreads();

    // Phase D: out[bv][f] = sum_k S[k] * W[k][f]
    // thread = (kg 0..31 owns 48 k's, fq 0..31 owns 4 f). S preloaded to regs.
    {
        const int fq = tid & 31;
        const int kg = tid >> 5;
        float4 sreg[12];
#pragma unroll
        for (int j = 0; j < 12; ++j)
            sreg[j] = *(const float4*)&s16[0][kg * 48 + j * 4];

        float4 acc = {0.f, 0.f, 0.f, 0.f};
        const float* Wp = W + (size_t)(kg * 48) * FF + fq * 4;
#pragma unroll
        for (int j = 0; j < 12; ++j) {
#pragma unroll
            for (int u = 0; u < 4; ++u) {
                const float sv = (u == 0) ? sreg[j].x : (u == 1) ? sreg[j].y
                               : (u == 2) ? sreg[j].z : sreg[j].w;
                const float4 w4 = *(const float4*)(Wp + (size_t)(j * 4 + u) * FF);
                acc.x += sv * w4.x; acc.y += sv * w4.y;
                acc.z += sv * w4.z; acc.w += sv * w4.w;
            }
        }
        *(float4*)&red[kg][fq * 4] = acc;
    }
    __syncthreads();
    if (tid < 512) {
        const int f = tid & 127, h = tid >> 7;
        float v = 0.f;
#pragma unroll
        for (int j = 0; j < 8; ++j) v += red[h * 8 + j][f];
        red2[h][f] = v;
    }
    __syncthreads();
    if (tid < FF)
        out[bv * FF + tid] = red2[0][tid] + red2[1][tid] + red2[2][tid] + red2[3][tid];
}

extern "C" void kernel_launch(void* const* d_in, const int* in_sizes, int n_in,
                              void* d_out, int out_size, void* d_ws, size_t ws_size,
                              hipStream_t stream) {
    const float* fe  = (const float*)d_in[0];  // feature_embed   (B,V,N,E)
    const float* ne  = (const float*)d_in[1];  // neighbour_embed (B,V,N,E)
    const int*   wi  = (const int*)d_in[2];    // w_index (B,V,N)
    const float* ind = (const float*)d_in[3];  // indicator (B,V,N)
    const float* W   = (const float*)d_in[4];  // (12,E,F)
    const float* a   = (const float*)d_in[5];  // (2F,1)
    float* out = (float*)d_out;                // (B,V,F)
    float* ws  = (float*)d_ws;

    prep_kernel<<<RK / 4, 256, 0, stream>>>(W, a, ws);
    gat_fused<<<BV, 1024, 0, stream>>>(fe, ne, wi, ind, W, ws, out);
}

// Round 15
// 23.661 us; speedup vs baseline: 1.8817x; 1.1016x over previous
//
#include <hip/hip_runtime.h>
#include <hip/hip_fp16.h>

#define NREL1  12   // NREL + 1 relation matrices
#define NN     128  // neighbours
#define EE     128  // in-features
#define FF     128  // out-features
#define BV     192  // B * V
#define RK     (NREL1 * EE)   // 1536

// ws layout (floats):
//   [0, 3072)        wa  (Wa1[12][128] | Wa2[12][128])
//   [4096, 102400)   W_h: W converted to __half, [k][f] row-major (196608 halves)
#define WS_WA  0
#define WS_WH  4096

// K0: wa rows (wave per (r,e), coalesced W read once aggregate) + W->fp16.
__global__ __launch_bounds__(256) void prep_kernel(const float* __restrict__ W,
                                                   const float* __restrict__ a,
                                                   float* __restrict__ ws) {
    const int w    = blockIdx.x * 4 + (threadIdx.x >> 6);  // 1536 waves
    const int lane = threadIdx.x & 63;
    const int r = w >> 7, e = w & 127;
    const float2 wv = *(const float2*)(W + (size_t)(r * EE + e) * FF + lane * 2);
    const float2 a1 = *(const float2*)(a + lane * 2);
    const float2 a2 = *(const float2*)(a + FF + lane * 2);
    float d1 = wv.x * a1.x + wv.y * a1.y;
    float d2 = wv.x * a2.x + wv.y * a2.y;
#pragma unroll
    for (int off = 32; off; off >>= 1) {
        d1 += __shfl_xor(d1, off);
        d2 += __shfl_xor(d2, off);
    }
    if (lane == 0) {
        ws[WS_WA + r * EE + e]      = d1;
        ws[WS_WA + RK + r * EE + e] = d2;
    }
    // W -> fp16 (each thread converts 2 consecutive floats)
    const int gid = blockIdx.x * 256 + threadIdx.x;   // 98304 threads
    const float2 wv2 = *(const float2*)(W + (size_t)2 * gid);
    ((__half2*)(ws + WS_WH))[gid] = __float22half2_rn(wv2);
}

// K1: block per bv, 1024 threads (16 waves).
// prefetch 8 edges/wave to regs -> logits (64-lane butterfly) -> per-wave
// redundant softmax (registers) -> wave-hoisted attn broadcast -> predicated
// scatter into per-wave LDS copy -> reduce 16 copies -> Phase D: out = S @ W_h
// (fp16 W, half the L2 stream; fp32 accumulate).
__global__ __launch_bounds__(1024) void gat_fused(const float* __restrict__ fe,
                                                  const float* __restrict__ ne,
                                                  const int* __restrict__ widx,
                                                  const float* __restrict__ ind,
                                                  const float* __restrict__ ws_r,
                                                  float* __restrict__ out) {
    __shared__ float wa[2 * RK];     // 12 KB
    __shared__ float s16[16][RK];    // 96 KB; s16[0] holds S after reduce
    __shared__ float red[32][FF];    // 16 KB
    __shared__ float red2[4][FF];    // 2 KB
    __shared__ float e_lds[NN];      // 0.5 KB
    __shared__ int   idx[NN];        // 0.5 KB

    const int bv   = blockIdx.x;
    const int tid  = threadIdx.x;
    const int wave = tid >> 6;
    const int lane = tid & 63;
    const int l32  = lane & 31;
    const int half = lane >> 5;   // 0: ne/wa1 side, 1: fe/wa2 side

    const float* ne_bv = ne + (size_t)bv * NN * EE;
    const float* fe_bv = fe + (size_t)bv * NN * EE;

    if (tid < NN) idx[tid] = widx[bv * NN + tid];

    // prefetch: 8 edges per wave, lane holds one e-quad of ne (or fe)
    float4 xr[8];
    {
        const float* base = (half ? fe_bv : ne_bv) + l32 * 4;
#pragma unroll
        for (int i = 0; i < 8; ++i)
            xr[i] = *(const float4*)(base + (wave * 8 + i) * EE);
    }

    // stage wa (L2) -> LDS (1 float4/thread); zero scatter copies (6/thread)
    if (tid < 2 * RK / 4)
        ((float4*)wa)[tid] = ((const float4*)(ws_r + WS_WA))[tid];
    {
        const float4 z = {0.f, 0.f, 0.f, 0.f};
#pragma unroll
        for (int q = 0; q < 6; ++q)
            ((float4*)&s16[0][0])[q * 1024 + tid] = z;
    }
    __syncthreads();

    // Phase A: logits; lanes<32 contribute ne.wa1, lanes>=32 fe.wa2
#pragma unroll
    for (int i = 0; i < 8; ++i) {
        const int n = wave * 8 + i;
        const int r = idx[n];
        const float4 wq = *(const float4*)&wa[half * RK + r * EE + l32 * 4];
        float d = xr[i].x * wq.x + xr[i].y * wq.y + xr[i].z * wq.z + xr[i].w * wq.w;
#pragma unroll
        for (int off = 32; off; off >>= 1) d += __shfl_xor(d, off);
        if (lane == 0) e_lds[n] = d > 0.f ? d : 0.2f * d;
    }
    __syncthreads();

    // Phase B: per-wave redundant softmax + indicator, registers only
    float a0, a1;
    {
        const float v0 = e_lds[lane], v1 = e_lds[lane + 64];
        float m = fmaxf(v0, v1);
#pragma unroll
        for (int off = 32; off; off >>= 1) m = fmaxf(m, __shfl_xor(m, off));
        const float ex0 = __expf(v0 - m), ex1 = __expf(v1 - m);
        float ss = ex0 + ex1;
#pragma unroll
        for (int off = 32; off; off >>= 1) ss += __shfl_xor(ss, off);
        const float inv = 1.f / ss;
        a0 = ex0 * inv * ind[bv * NN + lane];
        a1 = ex1 * inv * ind[bv * NN + lane + 64];
    }

    // attn broadcast for this wave's 8 edges: ALL 64 lanes participate
    float anv[8];
#pragma unroll
    for (int i = 0; i < 8; ++i) {
        const int n = wave * 8 + i;                        // wave-uniform
        anv[i] = (wave < 8) ? __shfl(a0, n) : __shfl(a1, n - 64);
    }

    // Phase C: predicated scatter from regs into this wave's private copy
    if (half == 0) {
        float* sc = s16[wave];
#pragma unroll
        for (int i = 0; i < 8; ++i) {
            const int n = wave * 8 + i;
            float* p = sc + idx[n] * EE + l32 * 4;
            float4 cur = *(const float4*)p;
            cur.x += anv[i] * xr[i].x; cur.y += anv[i] * xr[i].y;
            cur.z += anv[i] * xr[i].z; cur.w += anv[i] * xr[i].w;
            *(float4*)p = cur;
        }
    }
    __syncthreads();

    // reduce 16 copies -> S in s16[0] (in place)
    if (tid < RK / 4) {
        float4 v = *(const float4*)&s16[0][tid * 4];
#pragma unroll
        for (int c = 1; c < 16; ++c) {
            const float4 t = *(const float4*)&s16[c][tid * 4];
            v.x += t.x; v.y += t.y; v.z += t.z; v.w += t.w;
        }
        *(float4*)&s16[0][tid * 4] = v;
    }
    __syncthreads();

    // Phase D: out[bv][f] = sum_k S[k] * W_h[k][f]  (fp16 W, fp32 acc)
    // thread = (kg 0..31 owns 48 k's, fq 0..31 owns 4 f).
    {
        const int fq = tid & 31;
        const int kg = tid >> 5;
        float4 sreg[12];
#pragma unroll
        for (int j = 0; j < 12; ++j)
            sreg[j] = *(const float4*)&s16[0][kg * 48 + j * 4];

        const __half* Wh = (const __half*)(ws_r + WS_WH);
        const __half* Wp = Wh + (size_t)(kg * 48) * FF + fq * 4;
        float4 acc = {0.f, 0.f, 0.f, 0.f};
#pragma unroll
        for (int j = 0; j < 12; ++j) {
#pragma unroll
            for (int u = 0; u < 4; ++u) {
                const float sv = (u == 0) ? sreg[j].x : (u == 1) ? sreg[j].y
                               : (u == 2) ? sreg[j].z : sreg[j].w;
                // 4 halves = 8 B, aligned
                const float2 raw = *(const float2*)(Wp + (size_t)(j * 4 + u) * FF);
                const __half2* hp = (const __half2*)&raw;
                const float2 f01 = __half22float2(hp[0]);
                const float2 f23 = __half22float2(hp[1]);
                acc.x += sv * f01.x; acc.y += sv * f01.y;
                acc.z += sv * f23.x; acc.w += sv * f23.y;
            }
        }
        *(float4*)&red[kg][fq * 4] = acc;
    }
    __syncthreads();
    if (tid < 512) {
        const int f = tid & 127, h = tid >> 7;
        float v = 0.f;
#pragma unroll
        for (int j = 0; j < 8; ++j) v += red[h * 8 + j][f];
        red2[h][f] = v;
    }
    __syncthreads();
    if (tid < FF)
        out[bv * FF + tid] = red2[0][tid] + red2[1][tid] + red2[2][tid] + red2[3][tid];
}

extern "C" void kernel_launch(void* const* d_in, const int* in_sizes, int n_in,
                              void* d_out, int out_size, void* d_ws, size_t ws_size,
                              hipStream_t stream) {
    const float* fe  = (const float*)d_in[0];  // feature_embed   (B,V,N,E)
    const float* ne  = (const float*)d_in[1];  // neighbour_embed (B,V,N,E)
    const int*   wi  = (const int*)d_in[2];    // w_index (B,V,N)
    const float* ind = (const float*)d_in[3];  // indicator (B,V,N)
    const float* W   = (const float*)d_in[4];  // (12,E,F)
    const float* a   = (const float*)d_in[5];  // (2F,1)
    float* out = (float*)d_out;                // (B,V,F)
    float* ws  = (float*)d_ws;

    prep_kernel<<<RK / 4, 256, 0, stream>>>(W, a, ws);
    gat_fused<<<BV, 1024, 0, stream>>>(fe, ne, wi, ind, ws, out);
}